// Round 1
// 1981.131 us; speedup vs baseline: 3.3647x; 3.3647x over previous
//
#include <hip/hip_runtime.h>
#include <math.h>

#define H       256
#define TB      64      // samples per workgroup
#define NT      512     // threads per workgroup (8 waves)
#define NSTEPS  32
#define XS      264     // bf16 elems per activation row: 528B, 16B-aligned, low-conflict
#define DS1     260     // bf16 elems per d1 row: 520B, 8B-aligned

typedef __attribute__((ext_vector_type(8)))  short short8v;   // MFMA A/B frag: 8 bf16
typedef __attribute__((ext_vector_type(16))) float f32x16;    // MFMA C/D frag

__device__ __forceinline__ float fast_tanh(float x) {
    x = fminf(fmaxf(x, -15.0f), 15.0f);
    float e = __expf(2.0f * x);
    return 1.0f - 2.0f / (e + 1.0f);
}

// fp32 -> bf16 bits, round-to-nearest-even
__device__ __forceinline__ unsigned short f2b(float x) {
    unsigned u = __float_as_uint(x);
    u += 0x7FFFu + ((u >> 16) & 1u);
    return (unsigned short)(u >> 16);
}
__device__ __forceinline__ float b2f(unsigned short h) {
    return __uint_as_float(((unsigned)h) << 16);
}

// ---- pre-pass: fp32 W2,W3 -> bf16 row-major + transposed copies in d_ws ----
// ws layout (bf16 elems): W2b[0,64K) W3b[64K,128K) W2Tb[128K,192K) W3Tb[192K,256K)
__global__ void convert_w(const float* __restrict__ W2, const float* __restrict__ W3,
                          unsigned short* __restrict__ wsb) {
    int t = blockIdx.x * blockDim.x + threadIdx.x;   // 0..65535
    int i = t >> 8, j = t & 255;
    float w2 = W2[t], w3 = W3[t];
    wsb[t]                         = f2b(w2);
    wsb[65536 + t]                 = f2b(w3);
    wsb[131072 + (j << 8) + i]     = f2b(w2);   // W2T[j][i] = W2[i][j]
    wsb[196608 + (j << 8) + i]     = f2b(w3);
}

__global__ __launch_bounds__(NT, 2)
void sympnet_mfma(const float* __restrict__ t_eval,
                  const float* __restrict__ state0,
                  const float* __restrict__ W1, const float* __restrict__ b1,
                  const float* __restrict__ b2, const float* __restrict__ b3,
                  const float* __restrict__ W4, const float* __restrict__ scale_p,
                  const short* __restrict__ W2b,  const short* __restrict__ W3b,
                  const short* __restrict__ W2Tb, const short* __restrict__ W3Tb,
                  float* __restrict__ out)
{
    __shared__ unsigned short Xa[TB][XS];
    __shared__ unsigned short Xb[TB][XS];
    __shared__ unsigned short D1[TB][DS1];   // (1 - h1^2) bf16
    __shared__ float sS[TB][4];
    __shared__ float gp[8][TB][4];           // per-wave gradient partials

    const int tid  = threadIdx.x;
    const int lane = tid & 63;
    const int wv   = tid >> 6;      // wave 0..7
    const int col  = lane & 31;     // MFMA lane&31 index (M for A-frag, N for B/C)
    const int q    = lane >> 5;
    const int n0   = wv * 32;       // this wave's 32 output rows for every GEMM

    const float dt    = t_eval[1] - t_eval[0];
    const float scale = scale_p[0];
    const int   b0    = blockIdx.x * TB;

    // per-wave weight row base pointers (rows n0+col, k-slice q*8)
    const short* W2p  = W2b  + ((n0 + col) << 8) + q * 8;
    const short* W3p  = W3b  + ((n0 + col) << 8) + q * 8;
    const short* W3Tp = W3Tb + ((n0 + col) << 8) + q * 8;
    const short* W2Tp = W2Tb + ((n0 + col) << 8) + q * 8;

    if (tid < TB) {
        float4 s = reinterpret_cast<const float4*>(state0)[b0 + tid];
        sS[tid][0] = s.x; sS[tid][1] = s.y; sS[tid][2] = s.z; sS[tid][3] = s.w;
        reinterpret_cast<float4*>(out)[(size_t)(b0 + tid) * NSTEPS] = s;
    }
    __syncthreads();

    float d2[32];   // (1 - h2^2) for this wave's two sample-tiles, in registers

    for (int t = 1; t < NSTEPS; ++t) {
        // ================= L1 (VALU): h1 = tanh(s @ W1^T + b1) -> Xa, D1
        {
            const int j0  = (tid & 31) * 8;       // 32 dim-groups of 8
            const int i0v = (tid >> 5) * 4;       // 16 sample-groups of 4 (64 samples)
            float4 wvv[8];
            #pragma unroll
            for (int jj = 0; jj < 8; ++jj)
                wvv[jj] = reinterpret_cast<const float4*>(W1)[j0 + jj];
            float bb[8];
            {
                float4 a = *reinterpret_cast<const float4*>(&b1[j0]);
                float4 b = *reinterpret_cast<const float4*>(&b1[j0 + 4]);
                bb[0]=a.x; bb[1]=a.y; bb[2]=a.z; bb[3]=a.w;
                bb[4]=b.x; bb[5]=b.y; bb[6]=b.z; bb[7]=b.w;
            }
            #pragma unroll
            for (int ii = 0; ii < 4; ++ii) {
                float4 sv = *reinterpret_cast<const float4*>(&sS[i0v + ii][0]);
                unsigned short hb[8], db[8];
                #pragma unroll
                for (int jj = 0; jj < 8; ++jj) {
                    float z = bb[jj] + sv.x * wvv[jj].x + sv.y * wvv[jj].y
                                     + sv.z * wvv[jj].z + sv.w * wvv[jj].w;
                    float h = fast_tanh(z);
                    hb[jj] = f2b(h);
                    db[jj] = f2b(fmaf(-h, h, 1.0f));
                }
                *reinterpret_cast<short4*>(&Xa[i0v + ii][j0]) =
                    make_short4(hb[0], hb[1], hb[2], hb[3]);
                *reinterpret_cast<short4*>(&Xa[i0v + ii][j0 + 4]) =
                    make_short4(hb[4], hb[5], hb[6], hb[7]);
                *reinterpret_cast<short4*>(&D1[i0v + ii][j0]) =
                    make_short4(db[0], db[1], db[2], db[3]);
                *reinterpret_cast<short4*>(&D1[i0v + ii][j0 + 4]) =
                    make_short4(db[4], db[5], db[6], db[7]);
            }
        }
        __syncthreads();

        // ================= L2 (MFMA): h2 = tanh(W2 h1 + b2) -> Xb, d2 regs
        {
            short8v a[16];
            #pragma unroll
            for (int kc = 0; kc < 16; ++kc)
                a[kc] = *reinterpret_cast<const short8v*>(W2p + kc * 16);
            float4 bv4[4];
            #pragma unroll
            for (int g = 0; g < 4; ++g)
                bv4[g] = *reinterpret_cast<const float4*>(&b2[n0 + 8*g + 4*q]);
            f32x16 acc0 = {}, acc1 = {};
            #pragma unroll
            for (int kc = 0; kc < 16; ++kc) {
                short8v bA = *reinterpret_cast<const short8v*>(&Xa[col][kc*16 + q*8]);
                short8v bB = *reinterpret_cast<const short8v*>(&Xa[32 + col][kc*16 + q*8]);
                acc0 = __builtin_amdgcn_mfma_f32_32x32x16_bf16(a[kc], bA, acc0, 0, 0, 0);
                acc1 = __builtin_amdgcn_mfma_f32_32x32x16_bf16(a[kc], bB, acc1, 0, 0, 0);
            }
            #pragma unroll
            for (int mt = 0; mt < 2; ++mt) {
                f32x16 acc = (mt == 0) ? acc0 : acc1;
                #pragma unroll
                for (int g = 0; g < 4; ++g) {
                    const float* bp = reinterpret_cast<const float*>(&bv4[g]);
                    unsigned short hb[4];
                    #pragma unroll
                    for (int rr = 0; rr < 4; ++rr) {
                        float h = fast_tanh(acc[4*g + rr] + bp[rr]);
                        d2[mt*16 + 4*g + rr] = fmaf(-h, h, 1.0f);
                        hb[rr] = f2b(h);
                    }
                    *reinterpret_cast<short4*>(&Xb[mt*32 + col][n0 + 8*g + 4*q]) =
                        make_short4(hb[0], hb[1], hb[2], hb[3]);
                }
            }
        }
        __syncthreads();

        // ================= L3 (MFMA): u3 = W4 ⊙ (1 - tanh^2(W3 h2 + b3)) -> Xa
        {
            short8v a[16];
            #pragma unroll
            for (int kc = 0; kc < 16; ++kc)
                a[kc] = *reinterpret_cast<const short8v*>(W3p + kc * 16);
            float4 bv4[4], wv4[4];
            #pragma unroll
            for (int g = 0; g < 4; ++g) {
                bv4[g] = *reinterpret_cast<const float4*>(&b3[n0 + 8*g + 4*q]);
                wv4[g] = *reinterpret_cast<const float4*>(&W4[n0 + 8*g + 4*q]);
            }
            f32x16 acc0 = {}, acc1 = {};
            #pragma unroll
            for (int kc = 0; kc < 16; ++kc) {
                short8v bA = *reinterpret_cast<const short8v*>(&Xb[col][kc*16 + q*8]);
                short8v bB = *reinterpret_cast<const short8v*>(&Xb[32 + col][kc*16 + q*8]);
                acc0 = __builtin_amdgcn_mfma_f32_32x32x16_bf16(a[kc], bA, acc0, 0, 0, 0);
                acc1 = __builtin_amdgcn_mfma_f32_32x32x16_bf16(a[kc], bB, acc1, 0, 0, 0);
            }
            #pragma unroll
            for (int mt = 0; mt < 2; ++mt) {
                f32x16 acc = (mt == 0) ? acc0 : acc1;
                #pragma unroll
                for (int g = 0; g < 4; ++g) {
                    const float* bp = reinterpret_cast<const float*>(&bv4[g]);
                    const float* wp = reinterpret_cast<const float*>(&wv4[g]);
                    unsigned short ub[4];
                    #pragma unroll
                    for (int rr = 0; rr < 4; ++rr) {
                        float h = fast_tanh(acc[4*g + rr] + bp[rr]);
                        ub[rr] = f2b(wp[rr] * fmaf(-h, h, 1.0f));
                    }
                    *reinterpret_cast<short4*>(&Xa[mt*32 + col][n0 + 8*g + 4*q]) =
                        make_short4(ub[0], ub[1], ub[2], ub[3]);
                }
            }
        }
        __syncthreads();

        // ================= B1 (MFMA): u2 = (W3^T u3) ⊙ d2 -> Xb
        {
            short8v a[16];
            #pragma unroll
            for (int kc = 0; kc < 16; ++kc)
                a[kc] = *reinterpret_cast<const short8v*>(W3Tp + kc * 16);
            f32x16 acc0 = {}, acc1 = {};
            #pragma unroll
            for (int kc = 0; kc < 16; ++kc) {
                short8v bA = *reinterpret_cast<const short8v*>(&Xa[col][kc*16 + q*8]);
                short8v bB = *reinterpret_cast<const short8v*>(&Xa[32 + col][kc*16 + q*8]);
                acc0 = __builtin_amdgcn_mfma_f32_32x32x16_bf16(a[kc], bA, acc0, 0, 0, 0);
                acc1 = __builtin_amdgcn_mfma_f32_32x32x16_bf16(a[kc], bB, acc1, 0, 0, 0);
            }
            #pragma unroll
            for (int mt = 0; mt < 2; ++mt) {
                f32x16 acc = (mt == 0) ? acc0 : acc1;
                #pragma unroll
                for (int g = 0; g < 4; ++g) {
                    unsigned short ub[4];
                    #pragma unroll
                    for (int rr = 0; rr < 4; ++rr)
                        ub[rr] = f2b(acc[4*g + rr] * d2[mt*16 + 4*g + rr]);
                    *reinterpret_cast<short4*>(&Xb[mt*32 + col][n0 + 8*g + 4*q]) =
                        make_short4(ub[0], ub[1], ub[2], ub[3]);
                }
            }
        }
        __syncthreads();

        // ===== B2 (MFMA) + B3 fold: u1 = (W2^T u2) ⊙ d1; g[m][c] += u1·W1[n][c]
        {
            short8v a[16];
            #pragma unroll
            for (int kc = 0; kc < 16; ++kc)
                a[kc] = *reinterpret_cast<const short8v*>(W2Tp + kc * 16);
            f32x16 acc0 = {}, acc1 = {};
            #pragma unroll
            for (int kc = 0; kc < 16; ++kc) {
                short8v bA = *reinterpret_cast<const short8v*>(&Xb[col][kc*16 + q*8]);
                short8v bB = *reinterpret_cast<const short8v*>(&Xb[32 + col][kc*16 + q*8]);
                acc0 = __builtin_amdgcn_mfma_f32_32x32x16_bf16(a[kc], bA, acc0, 0, 0, 0);
                acc1 = __builtin_amdgcn_mfma_f32_32x32x16_bf16(a[kc], bB, acc1, 0, 0, 0);
            }
            float pg[2][4] = {};
            #pragma unroll
            for (int g = 0; g < 4; ++g) {
                float4 w1v[4];
                #pragma unroll
                for (int rr = 0; rr < 4; ++rr)
                    w1v[rr] = reinterpret_cast<const float4*>(W1)[n0 + 8*g + 4*q + rr];
                #pragma unroll
                for (int mt = 0; mt < 2; ++mt) {
                    f32x16 acc = (mt == 0) ? acc0 : acc1;
                    short4 dv = *reinterpret_cast<const short4*>(&D1[mt*32 + col][n0 + 8*g + 4*q]);
                    float dd[4] = { b2f((unsigned short)dv.x), b2f((unsigned short)dv.y),
                                    b2f((unsigned short)dv.z), b2f((unsigned short)dv.w) };
                    #pragma unroll
                    for (int rr = 0; rr < 4; ++rr) {
                        float u1 = acc[4*g + rr] * dd[rr];
                        float4 w = w1v[rr];
                        pg[mt][0] = fmaf(u1, w.x, pg[mt][0]);
                        pg[mt][1] = fmaf(u1, w.y, pg[mt][1]);
                        pg[mt][2] = fmaf(u1, w.z, pg[mt][2]);
                        pg[mt][3] = fmaf(u1, w.w, pg[mt][3]);
                    }
                }
            }
            // combine the two k-halves (q=0,1) within the wave, store per sample-tile
            #pragma unroll
            for (int mt = 0; mt < 2; ++mt) {
                float p0 = pg[mt][0], p1 = pg[mt][1], p2 = pg[mt][2], p3 = pg[mt][3];
                p0 += __shfl_xor(p0, 32); p1 += __shfl_xor(p1, 32);
                p2 += __shfl_xor(p2, 32); p3 += __shfl_xor(p3, 32);
                if (q == 0)
                    *reinterpret_cast<float4*>(&gp[wv][mt*32 + col][0]) =
                        make_float4(p0, p1, p2, p3);
            }
        }
        __syncthreads();

        // ================= state update (fp32 Verlet + correction)
        if (tid < TB) {
            float g0 = 0.f, g1 = 0.f, g2 = 0.f, g3 = 0.f;
            #pragma unroll
            for (int w = 0; w < 8; ++w) {
                float4 p = *reinterpret_cast<const float4*>(&gp[w][tid][0]);
                g0 += p.x; g1 += p.y; g2 += p.z; g3 += p.w;
            }
            float c0 = g1, c1 = -g0, c2 = g3, c3 = -g2;
            float nrm = sqrtf(c0*c0 + c1*c1 + c2*c2 + c3*c3);
            float ad  = dt * fminf(fmaxf(1.0f - 0.1f * nrm, 0.5f), 1.0f);
            float q1  = sS[tid][0], p1v = sS[tid][1];
            float q2  = sS[tid][2], p2v = sS[tid][3];
            float F1  = -q1 * (1.0f + 2.0f * q2);
            float F2  = -(q2 + q1 * q1 - q2 * q2);
            float p1h = p1v + 0.5f * dt * F1;
            float p2h = p2v + 0.5f * dt * F2;
            float q1n = q1 + dt * p1h;
            float q2n = q2 + dt * p2h;
            float F1n = -q1n * (1.0f + 2.0f * q2n);
            float F2n = -(q2n + q1n * q1n - q2n * q2n);
            float p1n = p1h + 0.5f * dt * F1n;
            float p2n = p2h + 0.5f * dt * F2n;
            float as  = ad * scale;
            float ns0 = q1n + as * c0;
            float ns1 = p1n + as * c1;
            float ns2 = q2n + as * c2;
            float ns3 = p2n + as * c3;
            sS[tid][0] = ns0; sS[tid][1] = ns1; sS[tid][2] = ns2; sS[tid][3] = ns3;
            reinterpret_cast<float4*>(out)[(size_t)(b0 + tid) * NSTEPS + t] =
                make_float4(ns0, ns1, ns2, ns3);
        }
        __syncthreads();
    }
}

extern "C" void kernel_launch(void* const* d_in, const int* in_sizes, int n_in,
                              void* d_out, int out_size, void* d_ws, size_t ws_size,
                              hipStream_t stream) {
    const float* t_eval = (const float*)d_in[0];
    const float* state0 = (const float*)d_in[1];
    const float* W1     = (const float*)d_in[2];
    const float* b1     = (const float*)d_in[3];
    const float* W2     = (const float*)d_in[4];
    const float* b2     = (const float*)d_in[5];
    const float* W3     = (const float*)d_in[6];
    const float* b3     = (const float*)d_in[7];
    const float* W4     = (const float*)d_in[8];
    const float* scale  = (const float*)d_in[10];
    float* out = (float*)d_out;

    unsigned short* wsb = (unsigned short*)d_ws;
    convert_w<<<dim3(256), dim3(256), 0, stream>>>(W2, W3, wsb);

    const short* W2b  = (const short*)(wsb);
    const short* W3b  = (const short*)(wsb + 65536);
    const short* W2Tb = (const short*)(wsb + 131072);
    const short* W3Tb = (const short*)(wsb + 196608);

    const int batch = in_sizes[1] / 4;   // 32768
    sympnet_mfma<<<dim3(batch / TB), dim3(NT), 0, stream>>>(
        t_eval, state0, W1, b1, b2, b3, W4, scale,
        W2b, W3b, W2Tb, W3Tb, out);
}

// Round 2
// 1662.811 us; speedup vs baseline: 4.0088x; 1.1914x over previous
//
#include <hip/hip_runtime.h>
#include <math.h>

#define H       256
#define TB      64      // samples per workgroup
#define NT      512     // threads per workgroup (8 waves)
#define NSTEPS  32
#define XS      264     // bf16 elems per activation row: 528B, 16B-aligned, low-conflict
#define DS1     260     // bf16 elems per d1 row: 520B, 8B-aligned

typedef __attribute__((ext_vector_type(8)))  short short8v;   // MFMA A/B frag: 8 bf16
typedef __attribute__((ext_vector_type(16))) float f32x16;    // MFMA C/D frag

__device__ __forceinline__ float fast_tanh(float x) {
    x = fminf(fmaxf(x, -15.0f), 15.0f);
    float e = exp2f(x * 2.8853900817779268f);   // exp(2x) = 2^(2x*log2e)
    return 1.0f - 2.0f / (e + 1.0f);
}

// fp32 -> bf16 bits, round-to-nearest-even
__device__ __forceinline__ unsigned short f2b(float x) {
    unsigned u = __float_as_uint(x);
    u += 0x7FFFu + ((u >> 16) & 1u);
    return (unsigned short)(u >> 16);
}
__device__ __forceinline__ float b2f(unsigned short h) {
    return __uint_as_float(((unsigned)h) << 16);
}

// ---- pre-pass: fp32 W2,W3 -> bf16 row-major + transposed copies in d_ws ----
// ws layout (bf16 elems): W2b[0,64K) W3b[64K,128K) W2Tb[128K,192K) W3Tb[192K,256K)
__global__ void convert_w(const float* __restrict__ W2, const float* __restrict__ W3,
                          unsigned short* __restrict__ wsb) {
    int t = blockIdx.x * blockDim.x + threadIdx.x;   // 0..65535
    int i = t >> 8, j = t & 255;
    float w2 = W2[t], w3 = W3[t];
    wsb[t]                         = f2b(w2);
    wsb[65536 + t]                 = f2b(w3);
    wsb[131072 + (j << 8) + i]     = f2b(w2);   // W2T[j][i] = W2[i][j]
    wsb[196608 + (j << 8) + i]     = f2b(w3);
}

// issue 16 global 16B loads of one 32x256 weight panel slice into registers
#define PREFETCH_W(dst, base)                                                  \
    _Pragma("unroll")                                                          \
    for (int kc = 0; kc < 16; ++kc)                                            \
        dst[kc] = *reinterpret_cast<const short8v*>((base) + kc * 16);

// dual-tile MFMA chain: A from register weight buffer, B from LDS activations
#define MFMA_CHAIN(WREG, XSRC, A0, A1)                                         \
    _Pragma("unroll")                                                          \
    for (int kc = 0; kc < 16; ++kc) {                                          \
        short8v bA = *reinterpret_cast<const short8v*>(&XSRC[col][kc*16 + q*8]);      \
        short8v bB = *reinterpret_cast<const short8v*>(&XSRC[32 + col][kc*16 + q*8]); \
        A0 = __builtin_amdgcn_mfma_f32_32x32x16_bf16(WREG[kc], bA, A0, 0, 0, 0);      \
        A1 = __builtin_amdgcn_mfma_f32_32x32x16_bf16(WREG[kc], bB, A1, 0, 0, 0);      \
    }

__global__ __launch_bounds__(NT, 2)
void sympnet_mfma(const float* __restrict__ t_eval,
                  const float* __restrict__ state0,
                  const float* __restrict__ W1, const float* __restrict__ b1,
                  const float* __restrict__ b2, const float* __restrict__ b3,
                  const float* __restrict__ W4, const float* __restrict__ scale_p,
                  const short* __restrict__ W2b,  const short* __restrict__ W3b,
                  const short* __restrict__ W2Tb, const short* __restrict__ W3Tb,
                  float* __restrict__ out)
{
    __shared__ unsigned short Xa[TB][XS];
    __shared__ unsigned short Xb[TB][XS];
    __shared__ unsigned short D1[TB][DS1];   // (1 - h1^2) bf16
    __shared__ float sS[TB][4];
    __shared__ float gp[8][TB][4];           // per-wave gradient partials
    __shared__ float sW1[H * 4];             // W1 rows, read broadcast in B2 fold
    __shared__ float sB2[H], sB3[H], sW4[H];

    const int tid  = threadIdx.x;
    const int lane = tid & 63;
    const int wv   = tid >> 6;      // wave 0..7
    const int col  = lane & 31;     // MFMA lane&31 index (M for A-frag, N for B/C)
    const int q    = lane >> 5;
    const int n0   = wv * 32;       // this wave's 32 output rows for every GEMM

    const float dt    = t_eval[1] - t_eval[0];
    const float scale = scale_p[0];
    const int   b0    = blockIdx.x * TB;

    // per-wave weight row base pointers (rows n0+col, k-slice q*8)
    const short* W2p  = W2b  + ((n0 + col) << 8) + q * 8;
    const short* W3p  = W3b  + ((n0 + col) << 8) + q * 8;
    const short* W3Tp = W3Tb + ((n0 + col) << 8) + q * 8;
    const short* W2Tp = W2Tb + ((n0 + col) << 8) + q * 8;

    // register double-buffer for weight fragments (prefetched one phase ahead)
    short8v wA[16], wB[16];
    PREFETCH_W(wA, W2p);            // W2 for the first L2 phase

    if (tid < H) {
        reinterpret_cast<float4*>(sW1)[tid] = reinterpret_cast<const float4*>(W1)[tid];
        sB2[tid] = b2[tid];
        sB3[tid] = b3[tid];
        sW4[tid] = W4[tid];
    }
    if (tid < TB) {
        float4 s = reinterpret_cast<const float4*>(state0)[b0 + tid];
        sS[tid][0] = s.x; sS[tid][1] = s.y; sS[tid][2] = s.z; sS[tid][3] = s.w;
        reinterpret_cast<float4*>(out)[(size_t)(b0 + tid) * NSTEPS] = s;
    }
    __syncthreads();

    float d2[32];   // (1 - h2^2) for this wave's two sample-tiles, in registers

    for (int t = 1; t < NSTEPS; ++t) {
        // ================= L1 (VALU): h1 = tanh(s @ W1^T + b1) -> Xa, D1
        {
            const int j0  = (tid & 31) * 8;       // 32 dim-groups of 8
            const int i0v = (tid >> 5) * 4;       // 16 sample-groups of 4 (64 samples)
            float4 wvv[8];
            #pragma unroll
            for (int jj = 0; jj < 8; ++jj)
                wvv[jj] = reinterpret_cast<const float4*>(W1)[j0 + jj];
            float bb[8];
            {
                float4 a = *reinterpret_cast<const float4*>(&b1[j0]);
                float4 b = *reinterpret_cast<const float4*>(&b1[j0 + 4]);
                bb[0]=a.x; bb[1]=a.y; bb[2]=a.z; bb[3]=a.w;
                bb[4]=b.x; bb[5]=b.y; bb[6]=b.z; bb[7]=b.w;
            }
            #pragma unroll
            for (int ii = 0; ii < 4; ++ii) {
                float4 sv = *reinterpret_cast<const float4*>(&sS[i0v + ii][0]);
                unsigned short hb[8], db[8];
                #pragma unroll
                for (int jj = 0; jj < 8; ++jj) {
                    float z = bb[jj] + sv.x * wvv[jj].x + sv.y * wvv[jj].y
                                     + sv.z * wvv[jj].z + sv.w * wvv[jj].w;
                    float h = fast_tanh(z);
                    hb[jj] = f2b(h);
                    db[jj] = f2b(fmaf(-h, h, 1.0f));
                }
                *reinterpret_cast<short4*>(&Xa[i0v + ii][j0]) =
                    make_short4(hb[0], hb[1], hb[2], hb[3]);
                *reinterpret_cast<short4*>(&Xa[i0v + ii][j0 + 4]) =
                    make_short4(hb[4], hb[5], hb[6], hb[7]);
                *reinterpret_cast<short4*>(&D1[i0v + ii][j0]) =
                    make_short4(db[0], db[1], db[2], db[3]);
                *reinterpret_cast<short4*>(&D1[i0v + ii][j0 + 4]) =
                    make_short4(db[4], db[5], db[6], db[7]);
            }
        }
        __syncthreads();

        // ================= L2 (MFMA): h2 = tanh(W2 h1 + b2) -> Xb, d2 regs
        {
            PREFETCH_W(wB, W3p);                 // cover W3 latency under this phase
            float4 bv4[4];
            #pragma unroll
            for (int g = 0; g < 4; ++g)
                bv4[g] = *reinterpret_cast<const float4*>(&sB2[n0 + 8*g + 4*q]);
            f32x16 acc0 = {}, acc1 = {};
            MFMA_CHAIN(wA, Xa, acc0, acc1);
            #pragma unroll
            for (int mt = 0; mt < 2; ++mt) {
                f32x16 acc = (mt == 0) ? acc0 : acc1;
                #pragma unroll
                for (int g = 0; g < 4; ++g) {
                    const float* bp = reinterpret_cast<const float*>(&bv4[g]);
                    unsigned short hb[4];
                    #pragma unroll
                    for (int rr = 0; rr < 4; ++rr) {
                        float h = fast_tanh(acc[4*g + rr] + bp[rr]);
                        d2[mt*16 + 4*g + rr] = fmaf(-h, h, 1.0f);
                        hb[rr] = f2b(h);
                    }
                    *reinterpret_cast<short4*>(&Xb[mt*32 + col][n0 + 8*g + 4*q]) =
                        make_short4(hb[0], hb[1], hb[2], hb[3]);
                }
            }
        }
        __syncthreads();

        // ================= L3 (MFMA): u3 = W4 ⊙ (1 - tanh^2(W3 h2 + b3)) -> Xa
        {
            PREFETCH_W(wA, W3Tp);                // cover W3^T latency
            float4 bv4[4], wv4[4];
            #pragma unroll
            for (int g = 0; g < 4; ++g) {
                bv4[g] = *reinterpret_cast<const float4*>(&sB3[n0 + 8*g + 4*q]);
                wv4[g] = *reinterpret_cast<const float4*>(&sW4[n0 + 8*g + 4*q]);
            }
            f32x16 acc0 = {}, acc1 = {};
            MFMA_CHAIN(wB, Xb, acc0, acc1);
            #pragma unroll
            for (int mt = 0; mt < 2; ++mt) {
                f32x16 acc = (mt == 0) ? acc0 : acc1;
                #pragma unroll
                for (int g = 0; g < 4; ++g) {
                    const float* bp = reinterpret_cast<const float*>(&bv4[g]);
                    const float* wp = reinterpret_cast<const float*>(&wv4[g]);
                    unsigned short ub[4];
                    #pragma unroll
                    for (int rr = 0; rr < 4; ++rr) {
                        float h = fast_tanh(acc[4*g + rr] + bp[rr]);
                        ub[rr] = f2b(wp[rr] * fmaf(-h, h, 1.0f));
                    }
                    *reinterpret_cast<short4*>(&Xa[mt*32 + col][n0 + 8*g + 4*q]) =
                        make_short4(ub[0], ub[1], ub[2], ub[3]);
                }
            }
        }
        __syncthreads();

        // ================= B1 (MFMA): u2 = (W3^T u3) ⊙ d2 -> Xb
        {
            PREFETCH_W(wB, W2Tp);                // cover W2^T latency
            f32x16 acc0 = {}, acc1 = {};
            MFMA_CHAIN(wA, Xa, acc0, acc1);
            #pragma unroll
            for (int mt = 0; mt < 2; ++mt) {
                f32x16 acc = (mt == 0) ? acc0 : acc1;
                #pragma unroll
                for (int g = 0; g < 4; ++g) {
                    unsigned short ub[4];
                    #pragma unroll
                    for (int rr = 0; rr < 4; ++rr)
                        ub[rr] = f2b(acc[4*g + rr] * d2[mt*16 + 4*g + rr]);
                    *reinterpret_cast<short4*>(&Xb[mt*32 + col][n0 + 8*g + 4*q]) =
                        make_short4(ub[0], ub[1], ub[2], ub[3]);
                }
            }
        }
        __syncthreads();

        // ===== B2 (MFMA) + B3 fold: u1 = (W2^T u2) ⊙ d1; g[m][c] += u1·W1[n][c]
        {
            PREFETCH_W(wA, W2p);                 // next step's W2, covered by update+L1
            f32x16 acc0 = {}, acc1 = {};
            MFMA_CHAIN(wB, Xb, acc0, acc1);
            float pg[2][4] = {};
            #pragma unroll
            for (int g = 0; g < 4; ++g) {
                float4 w1v[4];
                #pragma unroll
                for (int rr = 0; rr < 4; ++rr)
                    w1v[rr] = reinterpret_cast<const float4*>(sW1)[n0 + 8*g + 4*q + rr];
                #pragma unroll
                for (int mt = 0; mt < 2; ++mt) {
                    f32x16 acc = (mt == 0) ? acc0 : acc1;
                    short4 dv = *reinterpret_cast<const short4*>(&D1[mt*32 + col][n0 + 8*g + 4*q]);
                    float dd[4] = { b2f((unsigned short)dv.x), b2f((unsigned short)dv.y),
                                    b2f((unsigned short)dv.z), b2f((unsigned short)dv.w) };
                    #pragma unroll
                    for (int rr = 0; rr < 4; ++rr) {
                        float u1 = acc[4*g + rr] * dd[rr];
                        float4 w = w1v[rr];
                        pg[mt][0] = fmaf(u1, w.x, pg[mt][0]);
                        pg[mt][1] = fmaf(u1, w.y, pg[mt][1]);
                        pg[mt][2] = fmaf(u1, w.z, pg[mt][2]);
                        pg[mt][3] = fmaf(u1, w.w, pg[mt][3]);
                    }
                }
            }
            // combine the two k-halves (q=0,1) within the wave, store per sample-tile
            #pragma unroll
            for (int mt = 0; mt < 2; ++mt) {
                float p0 = pg[mt][0], p1 = pg[mt][1], p2 = pg[mt][2], p3 = pg[mt][3];
                p0 += __shfl_xor(p0, 32); p1 += __shfl_xor(p1, 32);
                p2 += __shfl_xor(p2, 32); p3 += __shfl_xor(p3, 32);
                if (q == 0)
                    *reinterpret_cast<float4*>(&gp[wv][mt*32 + col][0]) =
                        make_float4(p0, p1, p2, p3);
            }
        }
        __syncthreads();

        // ================= state update (fp32 Verlet + correction)
        if (tid < TB) {
            float g0 = 0.f, g1 = 0.f, g2 = 0.f, g3 = 0.f;
            #pragma unroll
            for (int w = 0; w < 8; ++w) {
                float4 p = *reinterpret_cast<const float4*>(&gp[w][tid][0]);
                g0 += p.x; g1 += p.y; g2 += p.z; g3 += p.w;
            }
            float c0 = g1, c1 = -g0, c2 = g3, c3 = -g2;
            float nrm = sqrtf(c0*c0 + c1*c1 + c2*c2 + c3*c3);
            float ad  = dt * fminf(fmaxf(1.0f - 0.1f * nrm, 0.5f), 1.0f);
            float q1  = sS[tid][0], p1v = sS[tid][1];
            float q2  = sS[tid][2], p2v = sS[tid][3];
            float F1  = -q1 * (1.0f + 2.0f * q2);
            float F2  = -(q2 + q1 * q1 - q2 * q2);
            float p1h = p1v + 0.5f * dt * F1;
            float p2h = p2v + 0.5f * dt * F2;
            float q1n = q1 + dt * p1h;
            float q2n = q2 + dt * p2h;
            float F1n = -q1n * (1.0f + 2.0f * q2n);
            float F2n = -(q2n + q1n * q1n - q2n * q2n);
            float p1n = p1h + 0.5f * dt * F1n;
            float p2n = p2h + 0.5f * dt * F2n;
            float as  = ad * scale;
            float ns0 = q1n + as * c0;
            float ns1 = p1n + as * c1;
            float ns2 = q2n + as * c2;
            float ns3 = p2n + as * c3;
            sS[tid][0] = ns0; sS[tid][1] = ns1; sS[tid][2] = ns2; sS[tid][3] = ns3;
            reinterpret_cast<float4*>(out)[(size_t)(b0 + tid) * NSTEPS + t] =
                make_float4(ns0, ns1, ns2, ns3);
        }
        __syncthreads();
    }
}

extern "C" void kernel_launch(void* const* d_in, const int* in_sizes, int n_in,
                              void* d_out, int out_size, void* d_ws, size_t ws_size,
                              hipStream_t stream) {
    const float* t_eval = (const float*)d_in[0];
    const float* state0 = (const float*)d_in[1];
    const float* W1     = (const float*)d_in[2];
    const float* b1     = (const float*)d_in[3];
    const float* W2     = (const float*)d_in[4];
    const float* b2     = (const float*)d_in[5];
    const float* W3     = (const float*)d_in[6];
    const float* b3     = (const float*)d_in[7];
    const float* W4     = (const float*)d_in[8];
    const float* scale  = (const float*)d_in[10];
    float* out = (float*)d_out;

    unsigned short* wsb = (unsigned short*)d_ws;
    convert_w<<<dim3(256), dim3(256), 0, stream>>>(W2, W3, wsb);

    const short* W2b  = (const short*)(wsb);
    const short* W3b  = (const short*)(wsb + 65536);
    const short* W2Tb = (const short*)(wsb + 131072);
    const short* W3Tb = (const short*)(wsb + 196608);

    const int batch = in_sizes[1] / 4;   // 32768
    sympnet_mfma<<<dim3(batch / TB), dim3(NT), 0, stream>>>(
        t_eval, state0, W1, b1, b2, b3, W4, scale,
        W2b, W3b, W2Tb, W3Tb, out);
}

// Round 3
// 1213.313 us; speedup vs baseline: 5.4940x; 1.3705x over previous
//
#include <hip/hip_runtime.h>
#include <hip/hip_bf16.h>
#include <math.h>

#define H       256
#define TB      64      // samples per workgroup
#define NT      512     // threads per workgroup (8 waves)
#define NSTEPS  32
#define XS      264     // bf16 elems per activation row: 528B, 16B-aligned, low-conflict
#define DS1     260     // bf16 elems per d1 row: 520B, 8B-aligned

typedef __attribute__((ext_vector_type(8)))  short short8v;   // MFMA A/B frag: 8 bf16
typedef __attribute__((ext_vector_type(16))) float f32x16;    // MFMA C/D frag

// tanh via v_exp + v_rcp: ~5 ops, 2 trans. No clamp needed:
//  x>>0: e=inf -> rcp(inf)=0 -> h=1 ;  x<<0: e=0 -> rcp(1)=1 -> h=-1.
__device__ __forceinline__ float fast_tanh(float x) {
    float e;
    asm("v_exp_f32 %0, %1" : "=v"(e) : "v"(x * 2.8853900817779268f)); // 2^(2x*log2e)
    return fmaf(-2.0f, __builtin_amdgcn_rcpf(e + 1.0f), 1.0f);
}

// pack 2 fp32 -> 1 u32 of 2 bf16, RNE (v_cvt_pk_bf16_f32)
__device__ __forceinline__ unsigned pk2(float lo, float hi) {
    __hip_bfloat162 h2 = __float22bfloat162_rn(make_float2(lo, hi));
    unsigned u; __builtin_memcpy(&u, &h2, 4);
    return u;
}
// fp32 -> bf16 bits, round-to-nearest-even (scalar, for the pre-pass)
__device__ __forceinline__ unsigned short f2b(float x) {
    unsigned u = __float_as_uint(x);
    u += 0x7FFFu + ((u >> 16) & 1u);
    return (unsigned short)(u >> 16);
}
__device__ __forceinline__ float b2f(unsigned short h) {
    return __uint_as_float(((unsigned)h) << 16);
}

// ---- pre-pass: fp32 W2,W3 -> bf16 row-major + transposed copies in d_ws ----
// ws layout (bf16 elems): W2b[0,64K) W3b[64K,128K) W2Tb[128K,192K) W3Tb[192K,256K)
__global__ void convert_w(const float* __restrict__ W2, const float* __restrict__ W3,
                          unsigned short* __restrict__ wsb) {
    int t = blockIdx.x * blockDim.x + threadIdx.x;   // 0..65535
    int i = t >> 8, j = t & 255;
    float w2 = W2[t], w3 = W3[t];
    wsb[t]                         = f2b(w2);
    wsb[65536 + t]                 = f2b(w3);
    wsb[131072 + (j << 8) + i]     = f2b(w2);   // W2T[j][i] = W2[i][j]
    wsb[196608 + (j << 8) + i]     = f2b(w3);
}

// issue 16 global 16B loads of one 32x256 weight panel slice into registers,
// then pin them in place (sched_barrier) so they can't sink into the MFMA chain
#define PREFETCH_W(dst, base)                                                  \
    _Pragma("unroll")                                                          \
    for (int kc = 0; kc < 16; ++kc)                                            \
        dst[kc] = *reinterpret_cast<const short8v*>((base) + kc * 16);         \
    __builtin_amdgcn_sched_barrier(0);

// dual-tile MFMA chain: A from register weight buffer, B from LDS activations
#define MFMA_CHAIN(WREG, XSRC, A0, A1)                                         \
    _Pragma("unroll")                                                          \
    for (int kc = 0; kc < 16; ++kc) {                                          \
        short8v bA = *reinterpret_cast<const short8v*>(&XSRC[col][kc*16 + q*8]);      \
        short8v bB = *reinterpret_cast<const short8v*>(&XSRC[32 + col][kc*16 + q*8]); \
        A0 = __builtin_amdgcn_mfma_f32_32x32x16_bf16(WREG[kc], bA, A0, 0, 0, 0);      \
        A1 = __builtin_amdgcn_mfma_f32_32x32x16_bf16(WREG[kc], bB, A1, 0, 0, 0);      \
    }

__global__ __launch_bounds__(NT, 2)
void sympnet_mfma(const float* __restrict__ t_eval,
                  const float* __restrict__ state0,
                  const float* __restrict__ W1, const float* __restrict__ b1,
                  const float* __restrict__ b2, const float* __restrict__ b3,
                  const float* __restrict__ W4, const float* __restrict__ scale_p,
                  const short* __restrict__ W2b,  const short* __restrict__ W3b,
                  const short* __restrict__ W2Tb, const short* __restrict__ W3Tb,
                  float* __restrict__ out)
{
    __shared__ unsigned short Xa[TB][XS];
    __shared__ unsigned short Xb[TB][XS];
    __shared__ unsigned short D1[TB][DS1];   // (1 - h1^2) bf16
    __shared__ float sS[TB][4];
    __shared__ float gp[8][TB][4];           // per-wave gradient partials
    __shared__ float sW1[H * 4];             // W1 rows (float4 each), L1 + B2 fold
    __shared__ float sB1[H], sB2[H], sB3[H], sW4[H];

    const int tid  = threadIdx.x;
    const int lane = tid & 63;
    const int wv   = tid >> 6;      // wave 0..7
    const int col  = lane & 31;     // MFMA lane&31 index (M for A-frag, N for B/C)
    const int q    = lane >> 5;
    const int n0   = wv * 32;       // this wave's 32 output rows for every GEMM

    const float dt    = t_eval[1] - t_eval[0];
    const float scale = scale_p[0];
    const int   b0    = blockIdx.x * TB;

    // per-wave weight row base pointers (rows n0+col, k-slice q*8)
    const short* W2p  = W2b  + ((n0 + col) << 8) + q * 8;
    const short* W3p  = W3b  + ((n0 + col) << 8) + q * 8;
    const short* W3Tp = W3Tb + ((n0 + col) << 8) + q * 8;
    const short* W2Tp = W2Tb + ((n0 + col) << 8) + q * 8;

    // register double-buffer for weight fragments (prefetched one phase ahead)
    short8v wA[16], wB[16];
    PREFETCH_W(wA, W2p);            // W2 for the first L2 phase

    if (tid < H) {
        reinterpret_cast<float4*>(sW1)[tid] = reinterpret_cast<const float4*>(W1)[tid];
        sB1[tid] = b1[tid];
        sB2[tid] = b2[tid];
        sB3[tid] = b3[tid];
        sW4[tid] = W4[tid];
    }
    if (tid < TB) {
        float4 s = reinterpret_cast<const float4*>(state0)[b0 + tid];
        sS[tid][0] = s.x; sS[tid][1] = s.y; sS[tid][2] = s.z; sS[tid][3] = s.w;
        reinterpret_cast<float4*>(out)[(size_t)(b0 + tid) * NSTEPS] = s;
    }
    __syncthreads();

    float d2[32];   // (1 - h2^2) for this wave's two sample-tiles, in registers

    for (int t = 1; t < NSTEPS; ++t) {
        // ================= L1 (VALU): h1 = tanh(s @ W1^T + b1) -> Xa, D1
        {
            const int j0  = (tid & 31) * 8;       // 32 dim-groups of 8
            const int i0v = (tid >> 5) * 4;       // 16 sample-groups of 4 (64 samples)
            float4 wvv[8];
            #pragma unroll
            for (int jj = 0; jj < 8; ++jj)
                wvv[jj] = reinterpret_cast<const float4*>(sW1)[j0 + jj];
            float bb[8];
            #pragma unroll
            for (int jj = 0; jj < 8; ++jj) bb[jj] = sB1[j0 + jj];
            #pragma unroll
            for (int ii = 0; ii < 4; ++ii) {
                float4 sv = *reinterpret_cast<const float4*>(&sS[i0v + ii][0]);
                float h[8], d[8];
                #pragma unroll
                for (int jj = 0; jj < 8; ++jj) {
                    float z = bb[jj] + sv.x * wvv[jj].x + sv.y * wvv[jj].y
                                     + sv.z * wvv[jj].z + sv.w * wvv[jj].w;
                    h[jj] = fast_tanh(z);
                    d[jj] = fmaf(-h[jj], h[jj], 1.0f);
                }
                *reinterpret_cast<uint2*>(&Xa[i0v + ii][j0]) =
                    make_uint2(pk2(h[0], h[1]), pk2(h[2], h[3]));
                *reinterpret_cast<uint2*>(&Xa[i0v + ii][j0 + 4]) =
                    make_uint2(pk2(h[4], h[5]), pk2(h[6], h[7]));
                *reinterpret_cast<uint2*>(&D1[i0v + ii][j0]) =
                    make_uint2(pk2(d[0], d[1]), pk2(d[2], d[3]));
                *reinterpret_cast<uint2*>(&D1[i0v + ii][j0 + 4]) =
                    make_uint2(pk2(d[4], d[5]), pk2(d[6], d[7]));
            }
        }
        __syncthreads();

        // ================= L2 (MFMA): h2 = tanh(W2 h1 + b2) -> Xb, d2 regs
        {
            PREFETCH_W(wB, W3p);                 // cover W3 latency under this phase
            float4 bv4[4];
            #pragma unroll
            for (int g = 0; g < 4; ++g)
                bv4[g] = *reinterpret_cast<const float4*>(&sB2[n0 + 8*g + 4*q]);
            f32x16 acc0 = {}, acc1 = {};
            MFMA_CHAIN(wA, Xa, acc0, acc1);
            #pragma unroll
            for (int mt = 0; mt < 2; ++mt) {
                f32x16 acc = (mt == 0) ? acc0 : acc1;
                #pragma unroll
                for (int g = 0; g < 4; ++g) {
                    const float* bp = reinterpret_cast<const float*>(&bv4[g]);
                    float h[4];
                    #pragma unroll
                    for (int rr = 0; rr < 4; ++rr) {
                        h[rr] = fast_tanh(acc[4*g + rr] + bp[rr]);
                        d2[mt*16 + 4*g + rr] = fmaf(-h[rr], h[rr], 1.0f);
                    }
                    *reinterpret_cast<uint2*>(&Xb[mt*32 + col][n0 + 8*g + 4*q]) =
                        make_uint2(pk2(h[0], h[1]), pk2(h[2], h[3]));
                }
            }
        }
        __syncthreads();

        // ================= L3 (MFMA): u3 = W4 ⊙ (1 - tanh^2(W3 h2 + b3)) -> Xa
        {
            PREFETCH_W(wA, W3Tp);                // cover W3^T latency
            float4 bv4[4], wv4[4];
            #pragma unroll
            for (int g = 0; g < 4; ++g) {
                bv4[g] = *reinterpret_cast<const float4*>(&sB3[n0 + 8*g + 4*q]);
                wv4[g] = *reinterpret_cast<const float4*>(&sW4[n0 + 8*g + 4*q]);
            }
            f32x16 acc0 = {}, acc1 = {};
            MFMA_CHAIN(wB, Xb, acc0, acc1);
            #pragma unroll
            for (int mt = 0; mt < 2; ++mt) {
                f32x16 acc = (mt == 0) ? acc0 : acc1;
                #pragma unroll
                for (int g = 0; g < 4; ++g) {
                    const float* bp = reinterpret_cast<const float*>(&bv4[g]);
                    const float* wp = reinterpret_cast<const float*>(&wv4[g]);
                    float u[4];
                    #pragma unroll
                    for (int rr = 0; rr < 4; ++rr) {
                        float h = fast_tanh(acc[4*g + rr] + bp[rr]);
                        u[rr] = wp[rr] * fmaf(-h, h, 1.0f);
                    }
                    *reinterpret_cast<uint2*>(&Xa[mt*32 + col][n0 + 8*g + 4*q]) =
                        make_uint2(pk2(u[0], u[1]), pk2(u[2], u[3]));
                }
            }
        }
        __syncthreads();

        // ================= B1 (MFMA): u2 = (W3^T u3) ⊙ d2 -> Xb
        {
            PREFETCH_W(wB, W2Tp);                // cover W2^T latency
            f32x16 acc0 = {}, acc1 = {};
            MFMA_CHAIN(wA, Xa, acc0, acc1);
            #pragma unroll
            for (int mt = 0; mt < 2; ++mt) {
                f32x16 acc = (mt == 0) ? acc0 : acc1;
                #pragma unroll
                for (int g = 0; g < 4; ++g) {
                    float u[4];
                    #pragma unroll
                    for (int rr = 0; rr < 4; ++rr)
                        u[rr] = acc[4*g + rr] * d2[mt*16 + 4*g + rr];
                    *reinterpret_cast<uint2*>(&Xb[mt*32 + col][n0 + 8*g + 4*q]) =
                        make_uint2(pk2(u[0], u[1]), pk2(u[2], u[3]));
                }
            }
        }
        __syncthreads();

        // ===== B2 (MFMA) + B3 fold: u1 = (W2^T u2) ⊙ d1; g[m][c] += u1·W1[n][c]
        {
            PREFETCH_W(wA, W2p);                 // next step's W2, covered by update+L1
            f32x16 acc0 = {}, acc1 = {};
            MFMA_CHAIN(wB, Xb, acc0, acc1);
            float pg[2][4] = {};
            #pragma unroll
            for (int g = 0; g < 4; ++g) {
                float4 w1v[4];
                #pragma unroll
                for (int rr = 0; rr < 4; ++rr)
                    w1v[rr] = reinterpret_cast<const float4*>(sW1)[n0 + 8*g + 4*q + rr];
                #pragma unroll
                for (int mt = 0; mt < 2; ++mt) {
                    f32x16 acc = (mt == 0) ? acc0 : acc1;
                    short4 dv = *reinterpret_cast<const short4*>(&D1[mt*32 + col][n0 + 8*g + 4*q]);
                    float dd[4] = { b2f((unsigned short)dv.x), b2f((unsigned short)dv.y),
                                    b2f((unsigned short)dv.z), b2f((unsigned short)dv.w) };
                    #pragma unroll
                    for (int rr = 0; rr < 4; ++rr) {
                        float u1 = acc[4*g + rr] * dd[rr];
                        float4 w = w1v[rr];
                        pg[mt][0] = fmaf(u1, w.x, pg[mt][0]);
                        pg[mt][1] = fmaf(u1, w.y, pg[mt][1]);
                        pg[mt][2] = fmaf(u1, w.z, pg[mt][2]);
                        pg[mt][3] = fmaf(u1, w.w, pg[mt][3]);
                    }
                }
            }
            // combine the two k-halves (q=0,1) within the wave, store per sample-tile
            #pragma unroll
            for (int mt = 0; mt < 2; ++mt) {
                float p0 = pg[mt][0], p1 = pg[mt][1], p2 = pg[mt][2], p3 = pg[mt][3];
                p0 += __shfl_xor(p0, 32); p1 += __shfl_xor(p1, 32);
                p2 += __shfl_xor(p2, 32); p3 += __shfl_xor(p3, 32);
                if (q == 0)
                    *reinterpret_cast<float4*>(&gp[wv][mt*32 + col][0]) =
                        make_float4(p0, p1, p2, p3);
            }
        }
        __syncthreads();

        // ================= state update (fp32 Verlet + correction)
        if (tid < TB) {
            float g0 = 0.f, g1 = 0.f, g2 = 0.f, g3 = 0.f;
            #pragma unroll
            for (int w = 0; w < 8; ++w) {
                float4 p = *reinterpret_cast<const float4*>(&gp[w][tid][0]);
                g0 += p.x; g1 += p.y; g2 += p.z; g3 += p.w;
            }
            float c0 = g1, c1 = -g0, c2 = g3, c3 = -g2;
            float nrm = sqrtf(c0*c0 + c1*c1 + c2*c2 + c3*c3);
            float ad  = dt * fminf(fmaxf(1.0f - 0.1f * nrm, 0.5f), 1.0f);
            float q1  = sS[tid][0], p1v = sS[tid][1];
            float q2  = sS[tid][2], p2v = sS[tid][3];
            float F1  = -q1 * (1.0f + 2.0f * q2);
            float F2  = -(q2 + q1 * q1 - q2 * q2);
            float p1h = p1v + 0.5f * dt * F1;
            float p2h = p2v + 0.5f * dt * F2;
            float q1n = q1 + dt * p1h;
            float q2n = q2 + dt * p2h;
            float F1n = -q1n * (1.0f + 2.0f * q2n);
            float F2n = -(q2n + q1n * q1n - q2n * q2n);
            float p1n = p1h + 0.5f * dt * F1n;
            float p2n = p2h + 0.5f * dt * F2n;
            float as  = ad * scale;
            float ns0 = q1n + as * c0;
            float ns1 = p1n + as * c1;
            float ns2 = q2n + as * c2;
            float ns3 = p2n + as * c3;
            sS[tid][0] = ns0; sS[tid][1] = ns1; sS[tid][2] = ns2; sS[tid][3] = ns3;
            reinterpret_cast<float4*>(out)[(size_t)(b0 + tid) * NSTEPS + t] =
                make_float4(ns0, ns1, ns2, ns3);
        }
        __syncthreads();
    }
}

extern "C" void kernel_launch(void* const* d_in, const int* in_sizes, int n_in,
                              void* d_out, int out_size, void* d_ws, size_t ws_size,
                              hipStream_t stream) {
    const float* t_eval = (const float*)d_in[0];
    const float* state0 = (const float*)d_in[1];
    const float* W1     = (const float*)d_in[2];
    const float* b1     = (const float*)d_in[3];
    const float* W2     = (const float*)d_in[4];
    const float* b2     = (const float*)d_in[5];
    const float* W3     = (const float*)d_in[6];
    const float* b3     = (const float*)d_in[7];
    const float* W4     = (const float*)d_in[8];
    const float* scale  = (const float*)d_in[10];
    float* out = (float*)d_out;

    unsigned short* wsb = (unsigned short*)d_ws;
    convert_w<<<dim3(256), dim3(256), 0, stream>>>(W2, W3, wsb);

    const short* W2b  = (const short*)(wsb);
    const short* W3b  = (const short*)(wsb + 65536);
    const short* W2Tb = (const short*)(wsb + 131072);
    const short* W3Tb = (const short*)(wsb + 196608);

    const int batch = in_sizes[1] / 4;   // 32768
    sympnet_mfma<<<dim3(batch / TB), dim3(NT), 0, stream>>>(
        t_eval, state0, W1, b1, b2, b3, W4, scale,
        W2b, W3b, W2Tb, W3Tb, out);
}